// Round 9
// baseline (44.629 us; speedup 1.0000x reference)
//
#include <hip/hip_runtime.h>

#define NT  128  // 2 waves/block; waves fully independent (zero __syncthreads)
#define WSZ 64
#define NJ  22

// parent table (compile-time indexed only)
constexpr int PARENT[NJ] = {0,0,0,0,1,2,3,4,5,6,7,8,9,9,9,12,13,14,16,17,18,19};

struct X9 { float r[9]; float t[3]; };

__device__ __forceinline__ void rodrigues(float ax, float ay, float az, float* R) {
    float sq   = ax*ax + ay*ay + az*az + 1e-12f;
    float rinv = rsqrtf(sq);
    float ang  = sq * rinv;          // sqrt(sq)
    float s, c;
    __sincosf(ang, &s, &c);
    float x = ax*rinv, y = ay*rinv, z = az*rinv;
    float t = 1.0f - c;
    R[0] = t*x*x + c;   R[1] = t*x*y - s*z; R[2] = t*x*z + s*y;
    R[3] = t*x*y + s*z; R[4] = t*y*y + c;   R[5] = t*y*z - s*x;
    R[6] = t*x*z - s*y; R[7] = t*y*z + s*x; R[8] = t*z*z + c;
}

// One FK step. Pose read from LDS (per-lane, stride-63); local position from
// REGISTERS (sk, compile-time index); output written back into the just-consumed
// pose slot (WAR-safe: per-wave DS pipe is in-order). Zero table traffic.
template<int J>
__device__ __forceinline__ X9 step(const X9& gp, float* pp, const float* sk) {
    float R[9];
    rodrigues(pp[(J-1)*3 + 0], pp[(J-1)*3 + 1], pp[(J-1)*3 + 2], R);
    const float l0 = sk[J*3+0], l1 = sk[J*3+1], l2 = sk[J*3+2];
    X9 g;
    #pragma unroll
    for (int r = 0; r < 3; ++r) {
        #pragma unroll
        for (int c = 0; c < 3; ++c)
            g.r[r*3+c] = fmaf(gp.r[r*3+0], R[c],
                         fmaf(gp.r[r*3+1], R[3+c],
                              gp.r[r*3+2] * R[6+c]));
        g.t[r] = fmaf(gp.r[r*3+0], l0,
                 fmaf(gp.r[r*3+1], l1,
                 fmaf(gp.r[r*3+2], l2, gp.t[r])));
    }
    pp[(J-1)*3+0] = g.t[0]; pp[(J-1)*3+1] = g.t[1]; pp[(J-1)*3+2] = g.t[2];
    return g;
}

__global__ __launch_bounds__(NT) void fk_joints_kernel(
    const float* __restrict__ body_pose,     // (S,63)
    const float* __restrict__ betas,         // (S,10)
    const float* __restrict__ global_orient, // (S,3)
    const float* __restrict__ transl,        // (S,3)
    const float* __restrict__ J_template,    // (22,3)   -> s_load (uniform idx)
    const float* __restrict__ J_shapedirs,   // (22,3,10)-> s_load (uniform idx)
    float* __restrict__ out)                 // (S,22,3)
{
    // Wave-private pose regions (64 samples x 63 floats). FK outputs for joint J
    // overwrite the pose slot (J-1) right after it is consumed. Root -> s_root.
    __shared__ float s_buf[NT*63];           // 32256 B
    __shared__ float s_root[NT*3];           // 1536 B   (total 33792 B -> 4 blk/CU)

    const int  tid  = threadIdx.x;
    const int  lane = tid & (WSZ-1);
    const int  wid  = tid >> 6;
    const long long sw = (long long)blockIdx.x * NT + (long long)wid * WSZ;
    const long long s  = sw + lane;

    float* myb = s_buf + wid * (WSZ*63);

    // ---- 1) stage OWN wave's pose chunk (coalesced float4) ----
    {
        const float4* src = reinterpret_cast<const float4*>(body_pose + sw*63);
        float4* dst = reinterpret_cast<float4*>(myb);
        for (int i = lane; i < WSZ*63/4; i += WSZ) dst[i] = src[i];   // 1008 f4
    }

    // ---- 2) per-lane small inputs (fill under staging) ----
    const float gox = global_orient[s*3 + 0];
    const float goy = global_orient[s*3 + 1];
    const float goz = global_orient[s*3 + 2];
    const float trx = transl[s*3 + 0];
    const float try_ = transl[s*3 + 1];
    const float trz = transl[s*3 + 2];
    float bt[10];
    {
        const float2* b2 = reinterpret_cast<const float2*>(betas + s*10);
        #pragma unroll
        for (int k = 0; k < 5; ++k) {
            float2 v = b2[k];
            bt[2*k+0] = v.x; bt[2*k+1] = v.y;
        }
    }

    // ---- 3) per-sample skeleton einsum IN REGISTERS; table via s_load/SGPR ----
    float sk[NJ*3];
    #pragma unroll
    for (int j = 0; j < NJ; ++j) {
        #pragma unroll
        for (int c = 0; c < 3; ++c) {
            float v = J_template[j*3 + c];                 // uniform -> SGPR
            #pragma unroll
            for (int k = 0; k < 10; ++k)
                v = fmaf(bt[k], J_shapedirs[(j*3 + c)*10 + k], v);  // v_fmac v,s,v
            sk[j*3 + c] = v;
        }
    }
    // parent diffs in-place (children have higher index; descend)
    #pragma unroll
    for (int j = NJ-1; j >= 1; --j) {
        #pragma unroll
        for (int c = 0; c < 3; ++c) sk[j*3 + c] -= sk[PARENT[j]*3 + c];
    }

    // ---- 4) root transform ----
    X9 g0;
    rodrigues(gox, goy, goz, g0.r);
    g0.t[0] = sk[0] + trx;
    g0.t[1] = sk[1] + try_;
    g0.t[2] = sk[2] + trz;
    s_root[tid*3+0] = g0.t[0]; s_root[tid*3+1] = g0.t[1]; s_root[tid*3+2] = g0.t[2];

    __builtin_amdgcn_wave_barrier();   // fence: staging writes before step pose reads

    // ---- 5) FK chains: pose from LDS per step, locals from regs, out in-place ----
    float* pp = myb + lane*63;

    X9 g;
    // chain A: 0 -> 1 -> 4 -> 7 -> 10
    g = step<1 >(g0, pp, sk);
    g = step<4 >(g,  pp, sk);
    g = step<7 >(g,  pp, sk);
    g = step<10>(g,  pp, sk);
    // chain B: 0 -> 2 -> 5 -> 8 -> 11
    g = step<2 >(g0, pp, sk);
    g = step<5 >(g,  pp, sk);
    g = step<8 >(g,  pp, sk);
    g = step<11>(g,  pp, sk);
    // chain C: 0 -> 3 -> 6 -> 9
    g = step<3 >(g0, pp, sk);
    g = step<6 >(g,  pp, sk);
    X9 g9 = step<9>(g, pp, sk);
    // chain D: 9 -> 12 -> 15
    g = step<12>(g9, pp, sk);
    g = step<15>(g,  pp, sk);
    // chain E: 9 -> 13 -> 16 -> 18 -> 20
    g = step<13>(g9, pp, sk);
    g = step<16>(g,  pp, sk);
    g = step<18>(g,  pp, sk);
    g = step<20>(g,  pp, sk);
    // chain F: 9 -> 14 -> 17 -> 19 -> 21
    g = step<14>(g9, pp, sk);
    g = step<17>(g,  pp, sk);
    g = step<19>(g,  pp, sk);
    g = step<21>(g,  pp, sk);

    __builtin_amdgcn_wave_barrier();   // fence: FK writes before gather reads

    // ---- 6) coalesced float4 gather of OWN wave's outputs ----
    // sample sm: root in s_root, joints 1..21 at myb[sm*63 + (j-1)*3 + c]
    {
        const float* s_rootw = s_root + wid * (WSZ*3);
        float4* dst = reinterpret_cast<float4*>(out + sw * (NJ*3));
        for (int i = lane; i < WSZ*66/4; i += WSZ) {     // 1056 f4
            const int f0 = i*4;
            float v[4];
            #pragma unroll
            for (int q = 0; q < 4; ++q) {
                int f = f0 + q;
                int sm = f / 66;
                int r = f - sm*66;
                v[q] = (r < 3) ? s_rootw[sm*3 + r] : myb[sm*63 + (r - 3)];
            }
            dst[i] = make_float4(v[0], v[1], v[2], v[3]);
        }
    }
}

extern "C" void kernel_launch(void* const* d_in, const int* in_sizes, int n_in,
                              void* d_out, int out_size, void* d_ws, size_t ws_size,
                              hipStream_t stream) {
    const float* body_pose     = (const float*)d_in[0];
    const float* betas         = (const float*)d_in[1];
    const float* global_orient = (const float*)d_in[2];
    const float* transl        = (const float*)d_in[3];
    const float* J_template    = (const float*)d_in[4];
    const float* J_shapedirs   = (const float*)d_in[5];
    float* out = (float*)d_out;

    const int S = in_sizes[0] / 63;        // B*L = 131072 (divisible by NT)
    const int blocks = S / NT;

    hipLaunchKernelGGL(fk_joints_kernel, dim3(blocks), dim3(NT), 0, stream,
                       body_pose, betas, global_orient, transl,
                       J_template, J_shapedirs, out);
}